// Round 2
// baseline (9281.872 us; speedup 1.0000x reference)
//
#include <hip/hip_runtime.h>
#include <math.h>

#define BATCH 4
#define SEQ 1024
#define DMODEL 1024
#define NHEADS 16
#define DHEAD 64
#define DFFDIM 4096
#define NLAYERS 2
#define MTOT (BATCH*SEQ)   // 4096 rows

// ---------------- embedding + positional encoding ----------------
__global__ __launch_bounds__(256) void k_embed(const int* __restrict__ ids,
                                               const float* __restrict__ emb,
                                               const float* __restrict__ pe,
                                               float* __restrict__ x) {
  int row = blockIdx.x;            // b*SEQ + l
  int l = row & (SEQ - 1);
  int tok = ids[row];
  const float4* e = (const float4*)(emb + (size_t)tok * DMODEL);
  const float4* p = (const float4*)(pe + (size_t)l * DMODEL);
  float4* o = (float4*)(x + (size_t)row * DMODEL);
  int i = threadIdx.x;             // 256 threads * float4 = 1024 floats
  float4 a = e[i], c = p[i];
  o[i] = make_float4(a.x + c.x, a.y + c.y, a.z + c.z, a.w + c.w);
}

// ---------------- generic fp32 GEMM: C[M,N] = A[M,K] @ W[K,N], optional relu ----------------
// 64x64 tile, BK=16, 256 threads, 4x4 acc per thread. All dims multiples of 64.
__global__ __launch_bounds__(256) void k_gemm(const float* __restrict__ A,
                                              const float* __restrict__ W,
                                              float* __restrict__ C,
                                              int Mdim, int Ndim, int Kdim, int relu) {
  __shared__ float As[16][65];   // [kk][m]
  __shared__ float Bs[16][65];   // [kk][n]
  const int tx = threadIdx.x & 15;
  const int ty = threadIdx.x >> 4;
  const int row0 = blockIdx.y * 64;
  const int col0 = blockIdx.x * 64;
  float acc[4][4] = {};
  for (int k0 = 0; k0 < Kdim; k0 += 16) {
    for (int i = threadIdx.x; i < 1024; i += 256) {
      int m = i >> 4, kk = i & 15;
      As[kk][m] = A[(size_t)(row0 + m) * Kdim + (k0 + kk)];
      int kk2 = i >> 6, n = i & 63;
      Bs[kk2][n] = W[(size_t)(k0 + kk2) * Ndim + (col0 + n)];
    }
    __syncthreads();
#pragma unroll
    for (int kk = 0; kk < 16; ++kk) {
      float a[4], bb[4];
#pragma unroll
      for (int i = 0; i < 4; ++i) a[i] = As[kk][ty * 4 + i];
#pragma unroll
      for (int j = 0; j < 4; ++j) bb[j] = Bs[kk][tx * 4 + j];
#pragma unroll
      for (int i = 0; i < 4; ++i)
#pragma unroll
        for (int j = 0; j < 4; ++j)
          acc[i][j] = fmaf(a[i], bb[j], acc[i][j]);
    }
    __syncthreads();
  }
#pragma unroll
  for (int i = 0; i < 4; ++i)
#pragma unroll
    for (int j = 0; j < 4; ++j) {
      float v = acc[i][j];
      if (relu) v = fmaxf(v, 0.f);
      C[(size_t)(row0 + ty * 4 + i) * Ndim + (col0 + tx * 4 + j)] = v;
    }
}

// ---------------- scores: S[b,h,i,j] = 0.125 * q_i . k_j  (masked -> -1e9) ----------------
// grid: (SEQ/64, SEQ/64, BATCH*NHEADS), 256 threads
__global__ __launch_bounds__(256) void k_scores(const float* __restrict__ q,
                                                const float* __restrict__ k,
                                                const int* __restrict__ ids,
                                                float* __restrict__ attn) {
  __shared__ float Qs[64][65];   // [row][d]
  __shared__ float Ks[64][65];   // [col][d]
  int bh = blockIdx.z;
  int b = bh >> 4, h = bh & 15;
  int row0 = blockIdx.y * 64, col0 = blockIdx.x * 64;
  const float* qb = q + (size_t)b * SEQ * DMODEL + h * DHEAD;
  const float* kb = k + (size_t)b * SEQ * DMODEL + h * DHEAD;
  for (int i = threadIdx.x; i < 4096; i += 256) {
    int r = i >> 6, c = i & 63;
    Qs[r][c] = qb[(size_t)(row0 + r) * DMODEL + c];
    Ks[r][c] = kb[(size_t)(col0 + r) * DMODEL + c];
  }
  __syncthreads();
  int tx = threadIdx.x & 15, ty = threadIdx.x >> 4;
  float acc[4][4] = {};
#pragma unroll 8
  for (int d = 0; d < 64; ++d) {
    float a[4], bb[4];
#pragma unroll
    for (int i = 0; i < 4; ++i) a[i] = Qs[ty * 4 + i][d];
#pragma unroll
    for (int j = 0; j < 4; ++j) bb[j] = Ks[tx * 4 + j][d];
#pragma unroll
    for (int i = 0; i < 4; ++i)
#pragma unroll
      for (int j = 0; j < 4; ++j)
        acc[i][j] = fmaf(a[i], bb[j], acc[i][j]);
  }
  float* ob = attn + (size_t)bh * SEQ * SEQ;
#pragma unroll
  for (int j = 0; j < 4; ++j) {
    int col = col0 + tx * 4 + j;
    bool msk = (ids[b * SEQ + col] == 0);
#pragma unroll
    for (int i = 0; i < 4; ++i) {
      float v = msk ? -1e9f : acc[i][j] * 0.125f;
      ob[(size_t)(row0 + ty * 4 + i) * SEQ + col] = v;
    }
  }
}

// ---------------- softmax in place over last dim (1024); one wave per row ----------------
__global__ __launch_bounds__(256) void k_softmax(float* __restrict__ a) {
  int row = blockIdx.x * 4 + (threadIdx.x >> 6);
  int lane = threadIdx.x & 63;
  float4* p = (float4*)(a + (size_t)row * SEQ);
  float4 v[4];
  float mx = -3e38f;
#pragma unroll
  for (int i = 0; i < 4; ++i) {
    v[i] = p[lane + 64 * i];
    mx = fmaxf(mx, fmaxf(fmaxf(v[i].x, v[i].y), fmaxf(v[i].z, v[i].w)));
  }
#pragma unroll
  for (int off = 32; off > 0; off >>= 1) mx = fmaxf(mx, __shfl_xor(mx, off, 64));
  float s = 0.f;
#pragma unroll
  for (int i = 0; i < 4; ++i) {
    v[i].x = __expf(v[i].x - mx); v[i].y = __expf(v[i].y - mx);
    v[i].z = __expf(v[i].z - mx); v[i].w = __expf(v[i].w - mx);
    s += v[i].x + v[i].y + v[i].z + v[i].w;
  }
#pragma unroll
  for (int off = 32; off > 0; off >>= 1) s += __shfl_xor(s, off, 64);
  float inv = 1.f / s;
#pragma unroll
  for (int i = 0; i < 4; ++i) {
    v[i].x *= inv; v[i].y *= inv; v[i].z *= inv; v[i].w *= inv;
    p[lane + 64 * i] = v[i];
  }
}

// ---------------- ctx = attn @ V per (b,h): [1024x1024]@[1024x64] ----------------
// grid: (SEQ/64, BATCH*NHEADS), 256 threads
__global__ __launch_bounds__(256) void k_pv(const float* __restrict__ attn,
                                            const float* __restrict__ v,
                                            float* __restrict__ ctx) {
  __shared__ float As[16][65];   // [kk][m]
  __shared__ float Bs[16][65];   // [kk][n]
  int bh = blockIdx.y;
  int b = bh >> 4, h = bh & 15;
  int row0 = blockIdx.x * 64;
  const float* ab = attn + (size_t)bh * SEQ * SEQ;
  const float* vb = v + (size_t)b * SEQ * DMODEL + h * DHEAD;
  int tx = threadIdx.x & 15, ty = threadIdx.x >> 4;
  float acc[4][4] = {};
  for (int k0 = 0; k0 < SEQ; k0 += 16) {
    for (int i = threadIdx.x; i < 1024; i += 256) {
      int m = i >> 4, kk = i & 15;
      As[kk][m] = ab[(size_t)(row0 + m) * SEQ + (k0 + kk)];
      int kk2 = i >> 6, n = i & 63;
      Bs[kk2][n] = vb[(size_t)(k0 + kk2) * DMODEL + n];
    }
    __syncthreads();
#pragma unroll
    for (int kk = 0; kk < 16; ++kk) {
      float a[4], bb[4];
#pragma unroll
      for (int i = 0; i < 4; ++i) a[i] = As[kk][ty * 4 + i];
#pragma unroll
      for (int j = 0; j < 4; ++j) bb[j] = Bs[kk][tx * 4 + j];
#pragma unroll
      for (int i = 0; i < 4; ++i)
#pragma unroll
        for (int j = 0; j < 4; ++j)
          acc[i][j] = fmaf(a[i], bb[j], acc[i][j]);
    }
    __syncthreads();
  }
  float* ob = ctx + (size_t)b * SEQ * DMODEL + h * DHEAD;
#pragma unroll
  for (int i = 0; i < 4; ++i)
#pragma unroll
    for (int j = 0; j < 4; ++j)
      ob[(size_t)(row0 + ty * 4 + i) * DMODEL + (tx * 4 + j)] = acc[i][j];
}

// ---------------- out = LayerNorm(t + xin); one wave per row ----------------
__global__ __launch_bounds__(256) void k_addln(const float* __restrict__ t,
                                               const float* __restrict__ xin,
                                               float* __restrict__ xout) {
  int row = blockIdx.x * 4 + (threadIdx.x >> 6);
  int lane = threadIdx.x & 63;
  const float4* tp = (const float4*)(t + (size_t)row * DMODEL);
  const float4* xp = (const float4*)(xin + (size_t)row * DMODEL);
  float4* op = (float4*)(xout + (size_t)row * DMODEL);
  float4 v[4];
  float s = 0.f;
#pragma unroll
  for (int i = 0; i < 4; ++i) {
    float4 a = tp[lane + 64 * i], c = xp[lane + 64 * i];
    v[i] = make_float4(a.x + c.x, a.y + c.y, a.z + c.z, a.w + c.w);
    s += v[i].x + v[i].y + v[i].z + v[i].w;
  }
#pragma unroll
  for (int off = 32; off > 0; off >>= 1) s += __shfl_xor(s, off, 64);
  float mu = s * (1.f / DMODEL);
  float ss = 0.f;
#pragma unroll
  for (int i = 0; i < 4; ++i) {
    float dx = v[i].x - mu, dy = v[i].y - mu, dz = v[i].z - mu, dw = v[i].w - mu;
    ss += dx * dx + dy * dy + dz * dz + dw * dw;
  }
#pragma unroll
  for (int off = 32; off > 0; off >>= 1) ss += __shfl_xor(ss, off, 64);
  float r = rsqrtf(ss * (1.f / DMODEL) + 1e-5f);
#pragma unroll
  for (int i = 0; i < 4; ++i)
    op[lane + 64 * i] = make_float4((v[i].x - mu) * r, (v[i].y - mu) * r,
                                    (v[i].z - mu) * r, (v[i].w - mu) * r);
}

extern "C" void kernel_launch(void* const* d_in, const int* in_sizes, int n_in,
                              void* d_out, int out_size, void* d_ws, size_t ws_size,
                              hipStream_t stream) {
  const int*   ids = (const int*)d_in[0];
  const float* emb = (const float*)d_in[1];
  const float* pe  = (const float*)d_in[2];
  const float* WQ  = (const float*)d_in[3];
  const float* WK  = (const float*)d_in[4];
  const float* WV  = (const float*)d_in[5];
  const float* WO  = (const float*)d_in[6];
  const float* W1  = (const float*)d_in[7];
  const float* W2  = (const float*)d_in[8];
  float* out = (float*)d_out;

  const size_t XSZ = (size_t)MTOT * DMODEL;        // 4M floats
  float* x    = (float*)d_ws;                      // 16 MB
  float* q    = x + XSZ;                           // 16 MB
  float* kbuf = q + XSZ;                           // 16 MB
  float* vbuf = kbuf + XSZ;                        // 16 MB
  float* hbuf = vbuf + XSZ;                        // 16 MB (1024 x 4096 FFN chunk)
  float* ctx  = q;                                 // q dead after scores
  float* tbuf = kbuf;                              // k dead after scores

  k_embed<<<MTOT, 256, 0, stream>>>(ids, emb, pe, x);

  for (int layer = 0; layer < NLAYERS; ++layer) {
    const float* wq = WQ + (size_t)layer * DMODEL * DMODEL;
    const float* wk = WK + (size_t)layer * DMODEL * DMODEL;
    const float* wv = WV + (size_t)layer * DMODEL * DMODEL;
    const float* wo = WO + (size_t)layer * DMODEL * DMODEL;
    const float* w1 = W1 + (size_t)layer * DMODEL * DFFDIM;
    const float* w2 = W2 + (size_t)layer * DFFDIM * DMODEL;

    dim3 gqkv(DMODEL / 64, MTOT / 64);
    k_gemm<<<gqkv, 256, 0, stream>>>(x, wq, q,    MTOT, DMODEL, DMODEL, 0);
    k_gemm<<<gqkv, 256, 0, stream>>>(x, wk, kbuf, MTOT, DMODEL, DMODEL, 0);
    k_gemm<<<gqkv, 256, 0, stream>>>(x, wv, vbuf, MTOT, DMODEL, DMODEL, 0);

    float* attn = out + XSZ + (size_t)layer * BATCH * NHEADS * SEQ * SEQ;
    dim3 gs(SEQ / 64, SEQ / 64, BATCH * NHEADS);
    k_scores<<<gs, 256, 0, stream>>>(q, kbuf, ids, attn);
    k_softmax<<<BATCH * NHEADS * SEQ / 4, 256, 0, stream>>>(attn);
    dim3 gp(SEQ / 64, BATCH * NHEADS);
    k_pv<<<gp, 256, 0, stream>>>(attn, vbuf, ctx);

    k_gemm<<<gqkv, 256, 0, stream>>>(ctx, wo, tbuf, MTOT, DMODEL, DMODEL, 0);
    k_addln<<<MTOT / 4, 256, 0, stream>>>(tbuf, x, x);

    // FFN in 4 row-chunks of 1024 (keeps hidden buffer at 16 MB)
    for (int mc = 0; mc < 4; ++mc) {
      const float* xrow = x + (size_t)mc * 1024 * DMODEL;
      float* trow = tbuf + (size_t)mc * 1024 * DMODEL;
      dim3 g1(DFFDIM / 64, 1024 / 64);
      k_gemm<<<g1, 256, 0, stream>>>(xrow, w1, hbuf, 1024, DFFDIM, DMODEL, 1);
      dim3 g2(DMODEL / 64, 1024 / 64);
      k_gemm<<<g2, 256, 0, stream>>>(hbuf, w2, trow, 1024, DMODEL, DFFDIM, 0);
    }
    float* xo = (layer == NLAYERS - 1) ? out : x;
    k_addln<<<MTOT / 4, 256, 0, stream>>>(tbuf, x, xo);
  }
}

// Round 3
// 2192.278 us; speedup vs baseline: 4.2339x; 4.2339x over previous
//
#include <hip/hip_runtime.h>
#include <hip/hip_bf16.h>
#include <math.h>

#define BATCH 4
#define SEQ 1024
#define DMODEL 1024
#define NHEADS 16
#define DHEAD 64
#define DFFDIM 4096
#define NLAYERS 2
#define MTOT (BATCH*SEQ)   // 4096 rows

typedef __hip_bfloat16 bf16;
typedef float f32x4 __attribute__((ext_vector_type(4)));
typedef short bf16x8 __attribute__((ext_vector_type(8)));  // 8 bf16 = 4 VGPRs

__device__ __forceinline__ unsigned short bfbits(float f) {
  bf16 h = __float2bfloat16(f);
  return *(unsigned short*)&h;
}

// ---------------- embedding + positional encoding (fp32 + bf16 mirror) ----------------
__global__ __launch_bounds__(256) void k_embed(const int* __restrict__ ids,
                                               const float* __restrict__ emb,
                                               const float* __restrict__ pe,
                                               float* __restrict__ x,
                                               bf16* __restrict__ xb) {
  int row = blockIdx.x;            // b*SEQ + l
  int l = row & (SEQ - 1);
  int tok = ids[row];
  const float4* e = (const float4*)(emb + (size_t)tok * DMODEL);
  const float4* p = (const float4*)(pe + (size_t)l * DMODEL);
  float4* o = (float4*)(x + (size_t)row * DMODEL);
  int i = threadIdx.x;             // 256 threads * float4 = 1024 floats
  float4 a = e[i], c = p[i];
  float4 r = make_float4(a.x + c.x, a.y + c.y, a.z + c.z, a.w + c.w);
  o[i] = r;
  ushort4 u;
  u.x = bfbits(r.x); u.y = bfbits(r.y); u.z = bfbits(r.z); u.w = bfbits(r.w);
  *(ushort4*)(xb + (size_t)row * DMODEL + i * 4) = u;
}

// ---------------- weight convert + transpose: W[K][N] f32 -> Wt[N][K] bf16 ----------------
// grid (N/32, K/32, NLAYERS), block 256
__global__ __launch_bounds__(256) void k_wcvt(const float* __restrict__ W,
                                              bf16* __restrict__ Wt,
                                              int Kdim, int Ndim) {
  __shared__ float t[32][33];
  const float* Ws = W + (size_t)blockIdx.z * Kdim * Ndim;
  bf16* Wd = Wt + (size_t)blockIdx.z * Kdim * Ndim;
  int n0 = blockIdx.x * 32, k0 = blockIdx.y * 32;
  int tx = threadIdx.x & 31, ty = threadIdx.x >> 5;   // ty 0..7
#pragma unroll
  for (int j = 0; j < 32; j += 8)
    t[ty + j][tx] = Ws[(size_t)(k0 + ty + j) * Ndim + n0 + tx];
  __syncthreads();
#pragma unroll
  for (int j = 0; j < 32; j += 8)
    Wd[(size_t)(n0 + ty + j) * Kdim + k0 + tx] = __float2bfloat16(t[tx][ty + j]);
}

// ---------------- MFMA GEMM: C[M,N] = A[M,K](bf16) @ Bt[N,K](bf16)^T ----------------
// 128x128 tile, BK=32, 256 threads = 4 waves (2x2 quadrants of 64x64).
// MODE 0: f32 out; 1: bf16 out; 2: bf16 out + relu
template<int MODE>
__global__ __launch_bounds__(256) void k_mfma_gemm(const bf16* __restrict__ A,
                                                   const bf16* __restrict__ Bt,
                                                   void* __restrict__ C,
                                                   int Mdim, int Ndim, int Kdim) {
  __shared__ __align__(16) short As[128 * 32];   // [row][k] 8KB
  __shared__ __align__(16) short Bs[128 * 32];   // [col][k] 8KB
  const int tid = threadIdx.x;
  const int wave = tid >> 6, lane = tid & 63;
  const int l15 = lane & 15, l4 = lane >> 4;
  const int row0 = blockIdx.y * 128, col0 = blockIdx.x * 128;
  const int wr = wave >> 1, wc = wave & 1;

  f32x4 acc[4][4] = {};

  for (int k0 = 0; k0 < Kdim; k0 += 32) {
#pragma unroll
    for (int i = 0; i < 2; ++i) {
      int c = i * 256 + tid;                 // chunk 0..511, 16B each
      int r = c >> 2, kc = (c & 3) * 8;
      const bf16* ga = A + (size_t)(row0 + r) * Kdim + k0 + kc;
      char* la = (char*)As + (i * 256 + wave * 64) * 16;
      __builtin_amdgcn_global_load_lds((const __attribute__((address_space(1))) void*)ga,
                                       (__attribute__((address_space(3))) void*)la, 16, 0, 0);
      const bf16* gb = Bt + (size_t)(col0 + r) * Kdim + k0 + kc;
      char* lb = (char*)Bs + (i * 256 + wave * 64) * 16;
      __builtin_amdgcn_global_load_lds((const __attribute__((address_space(1))) void*)gb,
                                       (__attribute__((address_space(3))) void*)lb, 16, 0, 0);
    }
    __syncthreads();
    bf16x8 af[4], bfr[4];
#pragma unroll
    for (int m = 0; m < 4; ++m)
      af[m] = *(const bf16x8*)&As[(wr * 64 + m * 16 + l15) * 32 + l4 * 8];
#pragma unroll
    for (int n = 0; n < 4; ++n)
      bfr[n] = *(const bf16x8*)&Bs[(wc * 64 + n * 16 + l15) * 32 + l4 * 8];
#pragma unroll
    for (int m = 0; m < 4; ++m)
#pragma unroll
      for (int n = 0; n < 4; ++n)
        acc[m][n] = __builtin_amdgcn_mfma_f32_16x16x32_bf16(af[m], bfr[n], acc[m][n], 0, 0, 0);
    __syncthreads();
  }

  // epilogue: D row=(lane>>4)*4+j, col=lane&15 within each 16x16 fragment [m89]
#pragma unroll
  for (int m = 0; m < 4; ++m) {
#pragma unroll
    for (int n = 0; n < 4; ++n) {
      int col = col0 + wc * 64 + n * 16 + l15;
#pragma unroll
      for (int j = 0; j < 4; ++j) {
        int row = row0 + wr * 64 + m * 16 + l4 * 4 + j;
        float v = acc[m][n][j];
        if (MODE == 2) v = fmaxf(v, 0.f);
        if (MODE == 0)
          ((float*)C)[(size_t)row * Ndim + col] = v;
        else
          ((bf16*)C)[(size_t)row * Ndim + col] = __float2bfloat16(v);
      }
    }
  }
}

// ---------------- scores: S[b,h,i,j] = 0.125 * q_i . k_j  (masked -> -1e9) ----------------
__global__ __launch_bounds__(256) void k_scores(const bf16* __restrict__ q,
                                                const bf16* __restrict__ k,
                                                const int* __restrict__ ids,
                                                float* __restrict__ attn) {
  __shared__ float Qs[64][65];
  __shared__ float Ks[64][65];
  int bh = blockIdx.z;
  int b = bh >> 4, h = bh & 15;
  int row0 = blockIdx.y * 64, col0 = blockIdx.x * 64;
  const bf16* qb = q + (size_t)b * SEQ * DMODEL + h * DHEAD;
  const bf16* kb = k + (size_t)b * SEQ * DMODEL + h * DHEAD;
  for (int i = threadIdx.x; i < 4096; i += 256) {
    int r = i >> 6, c = i & 63;
    Qs[r][c] = __bfloat162float(qb[(size_t)(row0 + r) * DMODEL + c]);
    Ks[r][c] = __bfloat162float(kb[(size_t)(col0 + r) * DMODEL + c]);
  }
  __syncthreads();
  int tx = threadIdx.x & 15, ty = threadIdx.x >> 4;
  float acc[4][4] = {};
#pragma unroll 8
  for (int d = 0; d < 64; ++d) {
    float a[4], bb[4];
#pragma unroll
    for (int i = 0; i < 4; ++i) a[i] = Qs[ty * 4 + i][d];
#pragma unroll
    for (int j = 0; j < 4; ++j) bb[j] = Ks[tx * 4 + j][d];
#pragma unroll
    for (int i = 0; i < 4; ++i)
#pragma unroll
      for (int j = 0; j < 4; ++j)
        acc[i][j] = fmaf(a[i], bb[j], acc[i][j]);
  }
  float* ob = attn + (size_t)bh * SEQ * SEQ;
#pragma unroll
  for (int j = 0; j < 4; ++j) {
    int col = col0 + tx * 4 + j;
    bool msk = (ids[b * SEQ + col] == 0);
#pragma unroll
    for (int i = 0; i < 4; ++i) {
      float v = msk ? -1e9f : acc[i][j] * 0.125f;
      ob[(size_t)(row0 + ty * 4 + i) * SEQ + col] = v;
    }
  }
}

// ---------------- softmax in place over last dim (1024); one wave per row ----------------
__global__ __launch_bounds__(256) void k_softmax(float* __restrict__ a) {
  int row = blockIdx.x * 4 + (threadIdx.x >> 6);
  int lane = threadIdx.x & 63;
  float4* p = (float4*)(a + (size_t)row * SEQ);
  float4 v[4];
  float mx = -3e38f;
#pragma unroll
  for (int i = 0; i < 4; ++i) {
    v[i] = p[lane + 64 * i];
    mx = fmaxf(mx, fmaxf(fmaxf(v[i].x, v[i].y), fmaxf(v[i].z, v[i].w)));
  }
#pragma unroll
  for (int off = 32; off > 0; off >>= 1) mx = fmaxf(mx, __shfl_xor(mx, off, 64));
  float s = 0.f;
#pragma unroll
  for (int i = 0; i < 4; ++i) {
    v[i].x = __expf(v[i].x - mx); v[i].y = __expf(v[i].y - mx);
    v[i].z = __expf(v[i].z - mx); v[i].w = __expf(v[i].w - mx);
    s += v[i].x + v[i].y + v[i].z + v[i].w;
  }
#pragma unroll
  for (int off = 32; off > 0; off >>= 1) s += __shfl_xor(s, off, 64);
  float inv = 1.f / s;
#pragma unroll
  for (int i = 0; i < 4; ++i) {
    v[i].x *= inv; v[i].y *= inv; v[i].z *= inv; v[i].w *= inv;
    p[lane + 64 * i] = v[i];
  }
}

// ---------------- ctx(bf16) = attn(f32) @ V(bf16) per (b,h) ----------------
__global__ __launch_bounds__(256) void k_pv(const float* __restrict__ attn,
                                            const bf16* __restrict__ v,
                                            bf16* __restrict__ ctx) {
  __shared__ float As_[16][65];
  __shared__ float Bs_[16][65];
  int bh = blockIdx.y;
  int b = bh >> 4, h = bh & 15;
  int row0 = blockIdx.x * 64;
  const float* ab = attn + (size_t)bh * SEQ * SEQ;
  const bf16* vb = v + (size_t)b * SEQ * DMODEL + h * DHEAD;
  int tx = threadIdx.x & 15, ty = threadIdx.x >> 4;
  float acc[4][4] = {};
  for (int k0 = 0; k0 < SEQ; k0 += 16) {
    for (int i = threadIdx.x; i < 1024; i += 256) {
      int m = i >> 4, kk = i & 15;
      As_[kk][m] = ab[(size_t)(row0 + m) * SEQ + (k0 + kk)];
      int kk2 = i >> 6, n = i & 63;
      Bs_[kk2][n] = __bfloat162float(vb[(size_t)(k0 + kk2) * DMODEL + n]);
    }
    __syncthreads();
#pragma unroll
    for (int kk = 0; kk < 16; ++kk) {
      float a[4], bb[4];
#pragma unroll
      for (int i = 0; i < 4; ++i) a[i] = As_[kk][ty * 4 + i];
#pragma unroll
      for (int j = 0; j < 4; ++j) bb[j] = Bs_[kk][tx * 4 + j];
#pragma unroll
      for (int i = 0; i < 4; ++i)
#pragma unroll
        for (int j = 0; j < 4; ++j)
          acc[i][j] = fmaf(a[i], bb[j], acc[i][j]);
    }
    __syncthreads();
  }
  bf16* ob = ctx + (size_t)b * SEQ * DMODEL + h * DHEAD;
#pragma unroll
  for (int i = 0; i < 4; ++i) {
    ushort4 u;
    u.x = bfbits(acc[i][0]); u.y = bfbits(acc[i][1]);
    u.z = bfbits(acc[i][2]); u.w = bfbits(acc[i][3]);
    *(ushort4*)&ob[(size_t)(row0 + ty * 4 + i) * DMODEL + tx * 4] = u;
  }
}

// ---------------- out = LayerNorm(t + xin) (fp32 + bf16 mirror) ----------------
__global__ __launch_bounds__(256) void k_addln(const float* __restrict__ t,
                                               const float* __restrict__ xin,
                                               float* __restrict__ xout,
                                               bf16* __restrict__ xbout) {
  int row = blockIdx.x * 4 + (threadIdx.x >> 6);
  int lane = threadIdx.x & 63;
  const float4* tp = (const float4*)(t + (size_t)row * DMODEL);
  const float4* xp = (const float4*)(xin + (size_t)row * DMODEL);
  float4* op = (float4*)(xout + (size_t)row * DMODEL);
  bf16* bp = xbout + (size_t)row * DMODEL;
  float4 v[4];
  float s = 0.f;
#pragma unroll
  for (int i = 0; i < 4; ++i) {
    float4 a = tp[lane + 64 * i], c = xp[lane + 64 * i];
    v[i] = make_float4(a.x + c.x, a.y + c.y, a.z + c.z, a.w + c.w);
    s += v[i].x + v[i].y + v[i].z + v[i].w;
  }
#pragma unroll
  for (int off = 32; off > 0; off >>= 1) s += __shfl_xor(s, off, 64);
  float mu = s * (1.f / DMODEL);
  float ss = 0.f;
#pragma unroll
  for (int i = 0; i < 4; ++i) {
    float dx = v[i].x - mu, dy = v[i].y - mu, dz = v[i].z - mu, dw = v[i].w - mu;
    ss += dx * dx + dy * dy + dz * dz + dw * dw;
  }
#pragma unroll
  for (int off = 32; off > 0; off >>= 1) ss += __shfl_xor(ss, off, 64);
  float r = rsqrtf(ss * (1.f / DMODEL) + 1e-5f);
#pragma unroll
  for (int i = 0; i < 4; ++i) {
    float4 o = make_float4((v[i].x - mu) * r, (v[i].y - mu) * r,
                           (v[i].z - mu) * r, (v[i].w - mu) * r);
    op[lane + 64 * i] = o;
    ushort4 u;
    u.x = bfbits(o.x); u.y = bfbits(o.y); u.z = bfbits(o.z); u.w = bfbits(o.w);
    *(ushort4*)&bp[(lane + 64 * i) * 4] = u;
  }
}

extern "C" void kernel_launch(void* const* d_in, const int* in_sizes, int n_in,
                              void* d_out, int out_size, void* d_ws, size_t ws_size,
                              hipStream_t stream) {
  const int*   ids = (const int*)d_in[0];
  const float* emb = (const float*)d_in[1];
  const float* pe  = (const float*)d_in[2];
  const float* WQ  = (const float*)d_in[3];
  const float* WK  = (const float*)d_in[4];
  const float* WV  = (const float*)d_in[5];
  const float* WO  = (const float*)d_in[6];
  const float* W1  = (const float*)d_in[7];
  const float* W2  = (const float*)d_in[8];
  float* out = (float*)d_out;

  const size_t MB = 1024 * 1024;
  char* ws = (char*)d_ws;
  float* x   = (float*)(ws);              // 16 MB fp32 residual stream
  float* t   = (float*)(ws + 16 * MB);    // 16 MB fp32 (WO / W2 outputs)
  bf16*  xb  = (bf16*)(ws + 32 * MB);     // 8 MB bf16 mirror of x
  bf16*  qb  = (bf16*)(ws + 40 * MB);     // 8 MB (Q, then ctx)
  bf16*  kb  = (bf16*)(ws + 48 * MB);     // 8 MB
  bf16*  vb  = (bf16*)(ws + 56 * MB);     // 8 MB
  bf16*  hb  = (bf16*)(ws + 64 * MB);     // 32 MB FFN hidden (4096x4096)
  bf16*  wqt = (bf16*)(ws + 96 * MB);     // 4 MB  (2 layers, [N][K])
  bf16*  wkt = (bf16*)(ws + 100 * MB);    // 4 MB
  bf16*  wvt = (bf16*)(ws + 104 * MB);    // 4 MB
  bf16*  wot = (bf16*)(ws + 108 * MB);    // 4 MB
  bf16*  w1t = (bf16*)(ws + 112 * MB);    // 16 MB
  bf16*  w2t = (bf16*)(ws + 128 * MB);    // 16 MB  -> 144 MB total

  // weights -> bf16, transposed to [N][K]
  k_wcvt<<<dim3(DMODEL / 32, DMODEL / 32, NLAYERS), 256, 0, stream>>>(WQ, wqt, DMODEL, DMODEL);
  k_wcvt<<<dim3(DMODEL / 32, DMODEL / 32, NLAYERS), 256, 0, stream>>>(WK, wkt, DMODEL, DMODEL);
  k_wcvt<<<dim3(DMODEL / 32, DMODEL / 32, NLAYERS), 256, 0, stream>>>(WV, wvt, DMODEL, DMODEL);
  k_wcvt<<<dim3(DMODEL / 32, DMODEL / 32, NLAYERS), 256, 0, stream>>>(WO, wot, DMODEL, DMODEL);
  k_wcvt<<<dim3(DFFDIM / 32, DMODEL / 32, NLAYERS), 256, 0, stream>>>(W1, w1t, DMODEL, DFFDIM);
  k_wcvt<<<dim3(DMODEL / 32, DFFDIM / 32, NLAYERS), 256, 0, stream>>>(W2, w2t, DFFDIM, DMODEL);

  k_embed<<<MTOT, 256, 0, stream>>>(ids, emb, pe, x, xb);

  for (int layer = 0; layer < NLAYERS; ++layer) {
    const bf16* lwq = wqt + (size_t)layer * DMODEL * DMODEL;
    const bf16* lwk = wkt + (size_t)layer * DMODEL * DMODEL;
    const bf16* lwv = wvt + (size_t)layer * DMODEL * DMODEL;
    const bf16* lwo = wot + (size_t)layer * DMODEL * DMODEL;
    const bf16* lw1 = w1t + (size_t)layer * DMODEL * DFFDIM;
    const bf16* lw2 = w2t + (size_t)layer * DFFDIM * DMODEL;

    dim3 gq(DMODEL / 128, MTOT / 128);           // (8, 32)
    k_mfma_gemm<1><<<gq, 256, 0, stream>>>(xb, lwq, qb, MTOT, DMODEL, DMODEL);
    k_mfma_gemm<1><<<gq, 256, 0, stream>>>(xb, lwk, kb, MTOT, DMODEL, DMODEL);
    k_mfma_gemm<1><<<gq, 256, 0, stream>>>(xb, lwv, vb, MTOT, DMODEL, DMODEL);

    float* attn = out + (size_t)MTOT * DMODEL + (size_t)layer * BATCH * NHEADS * SEQ * SEQ;
    dim3 gs(SEQ / 64, SEQ / 64, BATCH * NHEADS);
    k_scores<<<gs, 256, 0, stream>>>(qb, kb, ids, attn);
    k_softmax<<<BATCH * NHEADS * SEQ / 4, 256, 0, stream>>>(attn);
    dim3 gp(SEQ / 64, BATCH * NHEADS);
    k_pv<<<gp, 256, 0, stream>>>(attn, vb, qb);   // ctx -> qb (Q dead after scores)

    k_mfma_gemm<0><<<gq, 256, 0, stream>>>(qb, lwo, t, MTOT, DMODEL, DMODEL);
    k_addln<<<MTOT / 4, 256, 0, stream>>>(t, x, x, xb);

    dim3 g1(DFFDIM / 128, MTOT / 128);           // (32, 32)
    k_mfma_gemm<2><<<g1, 256, 0, stream>>>(xb, lw1, hb, MTOT, DFFDIM, DMODEL);
    dim3 g2(DMODEL / 128, MTOT / 128);           // (8, 32)
    k_mfma_gemm<0><<<g2, 256, 0, stream>>>(hb, lw2, t, MTOT, DMODEL, DFFDIM);

    float* xo = (layer == NLAYERS - 1) ? out : x;
    k_addln<<<MTOT / 4, 256, 0, stream>>>(t, x, xo, xb);
  }
}

// Round 4
// 1767.624 us; speedup vs baseline: 5.2510x; 1.2402x over previous
//
#include <hip/hip_runtime.h>
#include <hip/hip_bf16.h>
#include <math.h>

#define BATCH 4
#define SEQ 1024
#define DMODEL 1024
#define NHEADS 16
#define DHEAD 64
#define DFFDIM 4096
#define NLAYERS 2
#define MTOT (BATCH*SEQ)   // 4096 rows

typedef __hip_bfloat16 bf16;
typedef float f32x4 __attribute__((ext_vector_type(4)));
typedef short bf16x8 __attribute__((ext_vector_type(8)));  // 8 bf16 = 4 VGPRs

__device__ __forceinline__ unsigned short bfbits(float f) {
  bf16 h = __float2bfloat16(f);
  return *(unsigned short*)&h;
}

// ---------------- embedding + positional encoding (fp32 + bf16 mirror) ----------------
__global__ __launch_bounds__(256) void k_embed(const int* __restrict__ ids,
                                               const float* __restrict__ emb,
                                               const float* __restrict__ pe,
                                               float* __restrict__ x,
                                               bf16* __restrict__ xb) {
  int row = blockIdx.x;            // b*SEQ + l
  int l = row & (SEQ - 1);
  int tok = ids[row];
  const float4* e = (const float4*)(emb + (size_t)tok * DMODEL);
  const float4* p = (const float4*)(pe + (size_t)l * DMODEL);
  float4* o = (float4*)(x + (size_t)row * DMODEL);
  int i = threadIdx.x;
  float4 a = e[i], c = p[i];
  float4 r = make_float4(a.x + c.x, a.y + c.y, a.z + c.z, a.w + c.w);
  o[i] = r;
  ushort4 u;
  u.x = bfbits(r.x); u.y = bfbits(r.y); u.z = bfbits(r.z); u.w = bfbits(r.w);
  *(ushort4*)(xb + (size_t)row * DMODEL + i * 4) = u;
}

// ---------------- weight convert + transpose: W[K][N] f32 -> Wt[N][K] bf16 ----------------
__global__ __launch_bounds__(256) void k_wcvt(const float* __restrict__ W,
                                              bf16* __restrict__ Wt,
                                              int Kdim, int Ndim) {
  __shared__ float t[32][33];
  const float* Ws = W + (size_t)blockIdx.z * Kdim * Ndim;
  bf16* Wd = Wt + (size_t)blockIdx.z * Kdim * Ndim;
  int n0 = blockIdx.x * 32, k0 = blockIdx.y * 32;
  int tx = threadIdx.x & 31, ty = threadIdx.x >> 5;
#pragma unroll
  for (int j = 0; j < 32; j += 8)
    t[ty + j][tx] = Ws[(size_t)(k0 + ty + j) * Ndim + n0 + tx];
  __syncthreads();
#pragma unroll
  for (int j = 0; j < 32; j += 8)
    Wd[(size_t)(n0 + ty + j) * Kdim + k0 + tx] = __float2bfloat16(t[tx][ty + j]);
}

// ---------------- V transpose: vb[b][l][h*64+d] -> vt[bh][d][l] ----------------
__global__ __launch_bounds__(256) void k_vt(const bf16* __restrict__ v,
                                            bf16* __restrict__ vt) {
  __shared__ short t[32][33];
  int bh = blockIdx.z, b = bh >> 4, h = bh & 15;
  int l0 = blockIdx.x * 32, d0 = blockIdx.y * 32;
  int tx = threadIdx.x & 31, ty = threadIdx.x >> 5;
#pragma unroll
  for (int j = 0; j < 32; j += 8)
    t[ty + j][tx] = *(const short*)&v[(size_t)(b * SEQ + l0 + ty + j) * DMODEL + h * DHEAD + d0 + tx];
  __syncthreads();
#pragma unroll
  for (int j = 0; j < 32; j += 8)
    *(short*)&vt[((size_t)bh * DHEAD + d0 + ty + j) * SEQ + l0 + tx] = t[tx][ty + j];
}

// ---------------- MFMA GEMM: C[M,N] = A[M,K](bf16) @ Bt[N,K](bf16)^T ----------------
// 128x128 tile, BK=32, 256 threads = 4 waves (2x2 quadrants of 64x64).
// MODE 0: f32 out; 1: bf16 out; 2: bf16 out + relu
template<int MODE>
__global__ __launch_bounds__(256) void k_mfma_gemm(const bf16* __restrict__ A,
                                                   const bf16* __restrict__ Bt,
                                                   void* __restrict__ C,
                                                   int Mdim, int Ndim, int Kdim) {
  __shared__ __align__(16) short As[128 * 32];   // [row][k] 8KB
  __shared__ __align__(16) short Bs[128 * 32];   // [col][k] 8KB
  const int tid = threadIdx.x;
  const int wave = tid >> 6, lane = tid & 63;
  const int l15 = lane & 15, l4 = lane >> 4;
  const int row0 = blockIdx.y * 128, col0 = blockIdx.x * 128;
  const int wr = wave >> 1, wc = wave & 1;

  f32x4 acc[4][4] = {};

  for (int k0 = 0; k0 < Kdim; k0 += 32) {
#pragma unroll
    for (int i = 0; i < 2; ++i) {
      int c = i * 256 + tid;
      int r = c >> 2, kc = (c & 3) * 8;
      const bf16* ga = A + (size_t)(row0 + r) * Kdim + k0 + kc;
      char* la = (char*)As + (i * 256 + wave * 64) * 16;
      __builtin_amdgcn_global_load_lds((const __attribute__((address_space(1))) void*)ga,
                                       (__attribute__((address_space(3))) void*)la, 16, 0, 0);
      const bf16* gb = Bt + (size_t)(col0 + r) * Kdim + k0 + kc;
      char* lb = (char*)Bs + (i * 256 + wave * 64) * 16;
      __builtin_amdgcn_global_load_lds((const __attribute__((address_space(1))) void*)gb,
                                       (__attribute__((address_space(3))) void*)lb, 16, 0, 0);
    }
    __syncthreads();
    bf16x8 af[4], bfr[4];
#pragma unroll
    for (int m = 0; m < 4; ++m)
      af[m] = *(const bf16x8*)&As[(wr * 64 + m * 16 + l15) * 32 + l4 * 8];
#pragma unroll
    for (int n = 0; n < 4; ++n)
      bfr[n] = *(const bf16x8*)&Bs[(wc * 64 + n * 16 + l15) * 32 + l4 * 8];
#pragma unroll
    for (int m = 0; m < 4; ++m)
#pragma unroll
      for (int n = 0; n < 4; ++n)
        acc[m][n] = __builtin_amdgcn_mfma_f32_16x16x32_bf16(af[m], bfr[n], acc[m][n], 0, 0, 0);
    __syncthreads();
  }

#pragma unroll
  for (int m = 0; m < 4; ++m) {
#pragma unroll
    for (int n = 0; n < 4; ++n) {
      int col = col0 + wc * 64 + n * 16 + l15;
#pragma unroll
      for (int j = 0; j < 4; ++j) {
        int row = row0 + wr * 64 + m * 16 + l4 * 4 + j;
        float v = acc[m][n][j];
        if (MODE == 2) v = fmaxf(v, 0.f);
        if (MODE == 0)
          ((float*)C)[(size_t)row * Ndim + col] = v;
        else
          ((bf16*)C)[(size_t)row * Ndim + col] = __float2bfloat16(v);
      }
    }
  }
}

// ---------------- MFMA scores: S = 0.125 * Q.K^T (masked -> -1e9), raw f32 out ----------------
// grid (SEQ/128, SEQ/128, 64bh). K=64 single stage. XOR-swizzled LDS (T2, both-sides).
__global__ __launch_bounds__(256) void k_scores_mfma(const bf16* __restrict__ q,
                                                     const bf16* __restrict__ kin,
                                                     const int* __restrict__ ids,
                                                     float* __restrict__ attn) {
  __shared__ __align__(16) char As[128 * 128];  // 128 rows x 64 bf16
  __shared__ __align__(16) char Bs[128 * 128];
  const int tid = threadIdx.x;
  const int wave = tid >> 6;
  const int lane = tid & 63;
  const int l15 = lane & 15, l4 = lane >> 4;
  const int bh = blockIdx.z, b = bh >> 4, h = bh & 15;
  const int row0 = blockIdx.y * 128, col0 = blockIdx.x * 128;
  const int wr = wave >> 1, wc = wave & 1;
  const bf16* qb = q + (size_t)b * SEQ * DMODEL + h * DHEAD;
  const bf16* kb = kin + (size_t)b * SEQ * DMODEL + h * DHEAD;
  // stage: per operand 1024 chunks of 16B; source pre-swizzled, LDS linear
#pragma unroll
  for (int i = 0; i < 4; ++i) {
    int c = i * 256 + tid;
    int r = c >> 3;
    int kc = ((c ^ r) & 7) * 8;   // (c&7)^(r&7) chunk swizzle
    __builtin_amdgcn_global_load_lds(
        (const __attribute__((address_space(1))) void*)(qb + (size_t)(row0 + r) * DMODEL + kc),
        (__attribute__((address_space(3))) void*)(As + (size_t)(i * 256 + wave * 64) * 16), 16, 0, 0);
    __builtin_amdgcn_global_load_lds(
        (const __attribute__((address_space(1))) void*)(kb + (size_t)(col0 + r) * DMODEL + kc),
        (__attribute__((address_space(3))) void*)(Bs + (size_t)(i * 256 + wave * 64) * 16), 16, 0, 0);
  }
  __syncthreads();
  f32x4 acc[4][4] = {};
#pragma unroll
  for (int kk = 0; kk < 2; ++kk) {
    bf16x8 af[4], bfr[4];
    int j = l4 + kk * 4;
#pragma unroll
    for (int m = 0; m < 4; ++m) {
      int row = wr * 64 + m * 16 + l15;
      af[m] = *(const bf16x8*)(As + row * 128 + ((j ^ (row & 7)) * 16));
    }
#pragma unroll
    for (int n = 0; n < 4; ++n) {
      int row = wc * 64 + n * 16 + l15;
      bfr[n] = *(const bf16x8*)(Bs + row * 128 + ((j ^ (row & 7)) * 16));
    }
#pragma unroll
    for (int m = 0; m < 4; ++m)
#pragma unroll
      for (int n = 0; n < 4; ++n)
        acc[m][n] = __builtin_amdgcn_mfma_f32_16x16x32_bf16(af[m], bfr[n], acc[m][n], 0, 0, 0);
  }
  float* ob = attn + (size_t)bh * SEQ * SEQ;
#pragma unroll
  for (int n = 0; n < 4; ++n) {
    int col = col0 + wc * 64 + n * 16 + l15;
    bool msk = (ids[b * SEQ + col] == 0);
#pragma unroll
    for (int m = 0; m < 4; ++m)
#pragma unroll
      for (int j = 0; j < 4; ++j) {
        int row = row0 + wr * 64 + m * 16 + l4 * 4 + j;
        ob[(size_t)row * SEQ + col] = msk ? -1e9f : acc[m][n][j] * 0.125f;
      }
  }
}

// ---------------- softmax in place (f32) + bf16 mirror; one wave per row ----------------
__global__ __launch_bounds__(256) void k_softmax(float* __restrict__ a,
                                                 bf16* __restrict__ ab) {
  int row = blockIdx.x * 4 + (threadIdx.x >> 6);
  int lane = threadIdx.x & 63;
  float4* p = (float4*)(a + (size_t)row * SEQ);
  bf16* bp = ab + (size_t)row * SEQ;
  float4 v[4];
  float mx = -3e38f;
#pragma unroll
  for (int i = 0; i < 4; ++i) {
    v[i] = p[lane + 64 * i];
    mx = fmaxf(mx, fmaxf(fmaxf(v[i].x, v[i].y), fmaxf(v[i].z, v[i].w)));
  }
#pragma unroll
  for (int off = 32; off > 0; off >>= 1) mx = fmaxf(mx, __shfl_xor(mx, off, 64));
  float s = 0.f;
#pragma unroll
  for (int i = 0; i < 4; ++i) {
    v[i].x = __expf(v[i].x - mx); v[i].y = __expf(v[i].y - mx);
    v[i].z = __expf(v[i].z - mx); v[i].w = __expf(v[i].w - mx);
    s += v[i].x + v[i].y + v[i].z + v[i].w;
  }
#pragma unroll
  for (int off = 32; off > 0; off >>= 1) s += __shfl_xor(s, off, 64);
  float inv = 1.f / s;
#pragma unroll
  for (int i = 0; i < 4; ++i) {
    v[i].x *= inv; v[i].y *= inv; v[i].z *= inv; v[i].w *= inv;
    p[lane + 64 * i] = v[i];
    ushort4 u;
    u.x = bfbits(v[i].x); u.y = bfbits(v[i].y); u.z = bfbits(v[i].z); u.w = bfbits(v[i].w);
    *(ushort4*)&bp[(lane + 64 * i) * 4] = u;
  }
}

// ---------------- MFMA PV: ctx[bh rows][64] = P(bf16) @ Vt^T ----------------
// grid (SEQ/128, 64bh); 4 waves = 4 row-quadrants of 32; BK=64; swizzled LDS.
__global__ __launch_bounds__(256) void k_pv_mfma(const bf16* __restrict__ pb,  // [bh][1024][1024]
                                                 const bf16* __restrict__ vt,  // [bh][64][1024]
                                                 bf16* __restrict__ ctx) {
  __shared__ __align__(16) char As[128 * 128];  // 128 rows x 64 k
  __shared__ __align__(16) char Bs[64 * 128];   // 64 n x 64 k
  const int tid = threadIdx.x;
  const int wave = tid >> 6, lane = tid & 63;
  const int l15 = lane & 15, l4 = lane >> 4;
  const int bh = blockIdx.y, b = bh >> 4, h = bh & 15;
  const int row0 = blockIdx.x * 128;
  const bf16* arow = pb + (size_t)bh * SEQ * SEQ + (size_t)row0 * SEQ;
  const bf16* vrow = vt + (size_t)bh * DHEAD * SEQ;
  f32x4 acc[2][4] = {};
  for (int k0 = 0; k0 < SEQ; k0 += 64) {
#pragma unroll
    for (int i = 0; i < 4; ++i) {
      int c = i * 256 + tid;
      int r = c >> 3, kc = ((c ^ r) & 7) * 8;
      __builtin_amdgcn_global_load_lds(
          (const __attribute__((address_space(1))) void*)(arow + (size_t)r * SEQ + k0 + kc),
          (__attribute__((address_space(3))) void*)(As + (size_t)(i * 256 + wave * 64) * 16), 16, 0, 0);
    }
#pragma unroll
    for (int i = 0; i < 2; ++i) {
      int c = i * 256 + tid;
      int r = c >> 3, kc = ((c ^ r) & 7) * 8;
      __builtin_amdgcn_global_load_lds(
          (const __attribute__((address_space(1))) void*)(vrow + (size_t)r * SEQ + k0 + kc),
          (__attribute__((address_space(3))) void*)(Bs + (size_t)(i * 256 + wave * 64) * 16), 16, 0, 0);
    }
    __syncthreads();
#pragma unroll
    for (int kk = 0; kk < 2; ++kk) {
      bf16x8 af[2], bfr[4];
      int j = l4 + kk * 4;
#pragma unroll
      for (int m = 0; m < 2; ++m) {
        int row = wave * 32 + m * 16 + l15;
        af[m] = *(const bf16x8*)(As + row * 128 + ((j ^ (row & 7)) * 16));
      }
#pragma unroll
      for (int n = 0; n < 4; ++n) {
        int row = n * 16 + l15;
        bfr[n] = *(const bf16x8*)(Bs + row * 128 + ((j ^ (row & 7)) * 16));
      }
#pragma unroll
      for (int m = 0; m < 2; ++m)
#pragma unroll
        for (int n = 0; n < 4; ++n)
          acc[m][n] = __builtin_amdgcn_mfma_f32_16x16x32_bf16(af[m], bfr[n], acc[m][n], 0, 0, 0);
    }
    __syncthreads();
  }
  bf16* ob = ctx + (size_t)b * SEQ * DMODEL + h * DHEAD;
#pragma unroll
  for (int m = 0; m < 2; ++m)
#pragma unroll
    for (int n = 0; n < 4; ++n)
#pragma unroll
      for (int j = 0; j < 4; ++j) {
        int row = row0 + wave * 32 + m * 16 + l4 * 4 + j;
        ob[(size_t)row * DMODEL + n * 16 + l15] = __float2bfloat16(acc[m][n][j]);
      }
}

// ---------------- out = LayerNorm(t + xin) (fp32 + bf16 mirror) ----------------
__global__ __launch_bounds__(256) void k_addln(const float* __restrict__ t,
                                               const float* __restrict__ xin,
                                               float* __restrict__ xout,
                                               bf16* __restrict__ xbout) {
  int row = blockIdx.x * 4 + (threadIdx.x >> 6);
  int lane = threadIdx.x & 63;
  const float4* tp = (const float4*)(t + (size_t)row * DMODEL);
  const float4* xp = (const float4*)(xin + (size_t)row * DMODEL);
  float4* op = (float4*)(xout + (size_t)row * DMODEL);
  bf16* bp = xbout + (size_t)row * DMODEL;
  float4 v[4];
  float s = 0.f;
#pragma unroll
  for (int i = 0; i < 4; ++i) {
    float4 a = tp[lane + 64 * i], c = xp[lane + 64 * i];
    v[i] = make_float4(a.x + c.x, a.y + c.y, a.z + c.z, a.w + c.w);
    s += v[i].x + v[i].y + v[i].z + v[i].w;
  }
#pragma unroll
  for (int off = 32; off > 0; off >>= 1) s += __shfl_xor(s, off, 64);
  float mu = s * (1.f / DMODEL);
  float ss = 0.f;
#pragma unroll
  for (int i = 0; i < 4; ++i) {
    float dx = v[i].x - mu, dy = v[i].y - mu, dz = v[i].z - mu, dw = v[i].w - mu;
    ss += dx * dx + dy * dy + dz * dz + dw * dw;
  }
#pragma unroll
  for (int off = 32; off > 0; off >>= 1) ss += __shfl_xor(ss, off, 64);
  float r = rsqrtf(ss * (1.f / DMODEL) + 1e-5f);
#pragma unroll
  for (int i = 0; i < 4; ++i) {
    float4 o = make_float4((v[i].x - mu) * r, (v[i].y - mu) * r,
                           (v[i].z - mu) * r, (v[i].w - mu) * r);
    op[lane + 64 * i] = o;
    ushort4 u;
    u.x = bfbits(o.x); u.y = bfbits(o.y); u.z = bfbits(o.z); u.w = bfbits(o.w);
    *(ushort4*)&bp[(lane + 64 * i) * 4] = u;
  }
}

extern "C" void kernel_launch(void* const* d_in, const int* in_sizes, int n_in,
                              void* d_out, int out_size, void* d_ws, size_t ws_size,
                              hipStream_t stream) {
  const int*   ids = (const int*)d_in[0];
  const float* emb = (const float*)d_in[1];
  const float* pe  = (const float*)d_in[2];
  const float* WQ  = (const float*)d_in[3];
  const float* WK  = (const float*)d_in[4];
  const float* WV  = (const float*)d_in[5];
  const float* WO  = (const float*)d_in[6];
  const float* W1  = (const float*)d_in[7];
  const float* W2  = (const float*)d_in[8];
  float* out = (float*)d_out;

  const size_t MB = 1024 * 1024;
  char* ws = (char*)d_ws;
  float* x   = (float*)(ws);              // 16 MB fp32 residual stream
  float* t   = (float*)(ws + 16 * MB);    // 16 MB fp32 (WO / W2 outputs)
  bf16*  xb  = (bf16*)(ws + 32 * MB);     // 8 MB bf16 mirror of x
  bf16*  qb  = (bf16*)(ws + 40 * MB);     // 8 MB (Q, then ctx)
  bf16*  kb  = (bf16*)(ws + 48 * MB);     // 8 MB
  bf16*  vb  = (bf16*)(ws + 56 * MB);     // 8 MB
  bf16*  hb  = (bf16*)(ws + 64 * MB);     // 32 MB FFN hidden (4096x4096)
  bf16*  wqt = (bf16*)(ws + 96 * MB);     // 4 MB  (2 layers, [N][K])
  bf16*  wkt = (bf16*)(ws + 100 * MB);    // 4 MB
  bf16*  wvt = (bf16*)(ws + 104 * MB);    // 4 MB
  bf16*  wot = (bf16*)(ws + 108 * MB);    // 4 MB
  bf16*  w1t = (bf16*)(ws + 112 * MB);    // 16 MB
  bf16*  w2t = (bf16*)(ws + 128 * MB);    // 16 MB
  bf16*  vt  = (bf16*)(ws + 144 * MB);    // 8 MB  V^T per (b,h): [bh][64][1024]
  bf16*  pb  = (bf16*)(ws + 152 * MB);    // 128 MB bf16 attn probs (per layer, reused)
                                          // total 280 MB (ws ~2.2 GB per fill evidence)

  k_wcvt<<<dim3(DMODEL / 32, DMODEL / 32, NLAYERS), 256, 0, stream>>>(WQ, wqt, DMODEL, DMODEL);
  k_wcvt<<<dim3(DMODEL / 32, DMODEL / 32, NLAYERS), 256, 0, stream>>>(WK, wkt, DMODEL, DMODEL);
  k_wcvt<<<dim3(DMODEL / 32, DMODEL / 32, NLAYERS), 256, 0, stream>>>(WV, wvt, DMODEL, DMODEL);
  k_wcvt<<<dim3(DMODEL / 32, DMODEL / 32, NLAYERS), 256, 0, stream>>>(WO, wot, DMODEL, DMODEL);
  k_wcvt<<<dim3(DFFDIM / 32, DMODEL / 32, NLAYERS), 256, 0, stream>>>(W1, w1t, DMODEL, DFFDIM);
  k_wcvt<<<dim3(DMODEL / 32, DFFDIM / 32, NLAYERS), 256, 0, stream>>>(W2, w2t, DFFDIM, DMODEL);

  k_embed<<<MTOT, 256, 0, stream>>>(ids, emb, pe, x, xb);

  for (int layer = 0; layer < NLAYERS; ++layer) {
    const bf16* lwq = wqt + (size_t)layer * DMODEL * DMODEL;
    const bf16* lwk = wkt + (size_t)layer * DMODEL * DMODEL;
    const bf16* lwv = wvt + (size_t)layer * DMODEL * DMODEL;
    const bf16* lwo = wot + (size_t)layer * DMODEL * DMODEL;
    const bf16* lw1 = w1t + (size_t)layer * DMODEL * DFFDIM;
    const bf16* lw2 = w2t + (size_t)layer * DFFDIM * DMODEL;

    dim3 gq(DMODEL / 128, MTOT / 128);           // (8, 32)
    k_mfma_gemm<1><<<gq, 256, 0, stream>>>(xb, lwq, qb, MTOT, DMODEL, DMODEL);
    k_mfma_gemm<1><<<gq, 256, 0, stream>>>(xb, lwk, kb, MTOT, DMODEL, DMODEL);
    k_mfma_gemm<1><<<gq, 256, 0, stream>>>(xb, lwv, vb, MTOT, DMODEL, DMODEL);

    k_vt<<<dim3(SEQ / 32, DHEAD / 32, BATCH * NHEADS), 256, 0, stream>>>(vb, vt);

    float* attn = out + (size_t)MTOT * DMODEL + (size_t)layer * BATCH * NHEADS * SEQ * SEQ;
    dim3 gs(SEQ / 128, SEQ / 128, BATCH * NHEADS);
    k_scores_mfma<<<gs, 256, 0, stream>>>(qb, kb, ids, attn);
    k_softmax<<<BATCH * NHEADS * SEQ / 4, 256, 0, stream>>>(attn, pb);
    dim3 gp(SEQ / 128, BATCH * NHEADS);
    k_pv_mfma<<<gp, 256, 0, stream>>>(pb, vt, qb);   // ctx -> qb (Q dead after scores)

    k_mfma_gemm<0><<<gq, 256, 0, stream>>>(qb, lwo, t, MTOT, DMODEL, DMODEL);
    k_addln<<<MTOT / 4, 256, 0, stream>>>(t, x, x, xb);

    dim3 g1(DFFDIM / 128, MTOT / 128);           // (32, 32)
    k_mfma_gemm<2><<<g1, 256, 0, stream>>>(xb, lw1, hb, MTOT, DFFDIM, DMODEL);
    dim3 g2(DMODEL / 128, MTOT / 128);           // (8, 32)
    k_mfma_gemm<0><<<g2, 256, 0, stream>>>(hb, lw2, t, MTOT, DMODEL, DFFDIM);

    float* xo = (layer == NLAYERS - 1) ? out : x;
    k_addln<<<MTOT / 4, 256, 0, stream>>>(t, x, xo, xb);
  }
}